// Round 6
// baseline (551.968 us; speedup 1.0000x reference)
//
#include <hip/hip_runtime.h>
#include <math.h>

#define N_NODES 100000
#define N_EDGES 1600000
#define F_IN 256
#define F_H 128
#define F_OUT 40
#define SCAN_CHUNK 1024
#define NCHUNK ((N_NODES + SCAN_CHUNK - 1) / SCAN_CHUNK)   // 98

typedef __attribute__((ext_vector_type(8))) short bf16x8;
typedef __attribute__((ext_vector_type(4))) float floatx4;

__device__ __forceinline__ unsigned short f2bf(float f) {
    unsigned int u = __float_as_uint(f);
    u += 0x7fffu + ((u >> 16) & 1u);          // RNE (finite inputs)
    return (unsigned short)(u >> 16);
}
__device__ __forceinline__ float bf_lo(unsigned int u) { return __uint_as_float(u << 16); }
__device__ __forceinline__ float bf_hi(unsigned int u) { return __uint_as_float(u & 0xffff0000u); }
__device__ __forceinline__ float bf2f(unsigned short s) { return __uint_as_float(((unsigned int)s) << 16); }

// ---- zero int array ----
__global__ void k_zero(int* p, int n) {
    int i = blockIdx.x * blockDim.x + threadIdx.x;
    if (i < n) p[i] = 0;
}

// ---- int degree count over dst ----
__global__ void k_deg(const int* __restrict__ eidx, int* degi) {
    int e = blockIdx.x * blockDim.x + threadIdx.x;
    if (e < N_EDGES) atomicAdd(&degi[eidx[N_EDGES + e]], 1);
}

// ---- dinv = rsqrt(deg + 1 [self-loop]) ----
__global__ void k_dinv(const int* __restrict__ degi, float* __restrict__ dinv) {
    int i = blockIdx.x * blockDim.x + threadIdx.x;
    if (i < N_NODES) dinv[i] = rsqrtf((float)degi[i] + 1.0f);
}

// ---- scan level 1 ----
__global__ __launch_bounds__(256) void k_chunk_sums(const int* __restrict__ degi,
                                                    int* __restrict__ chunkSums) {
    __shared__ int lds[256];
    int b = blockIdx.x, t = threadIdx.x;
    int base = b * SCAN_CHUNK;
    int s = 0;
#pragma unroll
    for (int j = 0; j < 4; ++j) {
        int i = base + j * 256 + t;
        if (i < N_NODES) s += degi[i];
    }
    lds[t] = s;
    __syncthreads();
    for (int off = 128; off > 0; off >>= 1) {
        if (t < off) lds[t] += lds[t + off];
        __syncthreads();
    }
    if (t == 0) chunkSums[b] = lds[0];
}

// ---- scan level 2 ----
__global__ __launch_bounds__(128) void k_scan_sums(int* chunkSums) {
    __shared__ int lds[NCHUNK];
    int t = threadIdx.x;
    if (t < NCHUNK) lds[t] = chunkSums[t];
    __syncthreads();
    if (t == 0) {
        int run = 0;
        for (int i = 0; i < NCHUNK; ++i) { int c = lds[i]; lds[i] = run; run += c; }
    }
    __syncthreads();
    if (t < NCHUNK) chunkSums[t] = lds[t];
}

// ---- scan level 3 ----
__global__ __launch_bounds__(256) void k_scan_final(const int* __restrict__ degi,
                                                    const int* __restrict__ chunkOff,
                                                    int* __restrict__ rowptr,
                                                    int* __restrict__ cursor) {
    __shared__ int tsum[256];
    int b = blockIdx.x, t = threadIdx.x;
    int base = b * SCAN_CHUNK;
    int v[4];
    int s = 0;
#pragma unroll
    for (int j = 0; j < 4; ++j) {
        int i = base + t * 4 + j;
        v[j] = (i < N_NODES) ? degi[i] : 0;
        s += v[j];
    }
    tsum[t] = s;
    __syncthreads();
    for (int off = 1; off < 256; off <<= 1) {
        int val = 0;
        if (t >= off) val = tsum[t - off];
        __syncthreads();
        if (t >= off) tsum[t] += val;
        __syncthreads();
    }
    int run = chunkOff[b] + ((t == 0) ? 0 : tsum[t - 1]);
#pragma unroll
    for (int j = 0; j < 4; ++j) {
        int i = base + t * 4 + j;
        if (i < N_NODES) { rowptr[i] = run; cursor[i] = run; }
        run += v[j];
    }
    if (b == 0 && t == 0) rowptr[N_NODES] = N_EDGES;
}

// ---- CSR fill: only src indices (norm is factorized away) ----
__global__ void k_fill(const int* __restrict__ eidx, int* cursor, int* __restrict__ csr_src) {
    int e = blockIdx.x * blockDim.x + threadIdx.x;
    if (e >= N_EDGES) return;
    int s = eidx[e], d = eidx[N_EDGES + e];
    int pos = atomicAdd(&cursor[d], 1);
    csr_src[pos] = s;
}

// ---- W1 [256][128] fp32 -> W1t [128][256] bf16 ----
__global__ void k_cvt_w1(const float* __restrict__ W1, short* __restrict__ W1t) {
    int idx = blockIdx.x * blockDim.x + threadIdx.x;   // 32768
    int n = idx >> 8, k = idx & 255;
    W1t[n * 256 + k] = (short)f2bf(W1[k * 128 + n]);
}

// ---- W2 [128][40] fp32 -> W2t [48][128] bf16 (zero-padded cols 40..47) ----
__global__ void k_cvt_w2(const float* __restrict__ W2, short* __restrict__ W2t) {
    int idx = blockIdx.x * blockDim.x + threadIdx.x;   // 6144
    if (idx >= 48 * 128) return;
    int n = idx >> 7, k = idx & 127;
    float v = (n < F_OUT) ? W2[k * F_OUT + n] : 0.f;
    W2t[n * 128 + k] = (short)f2bf(v);
}

// ---- GEMM1 (MFMA bf16): h1b[N,128](bf16) = dinv[row] * (x[N,256] @ W1) ----
__global__ __launch_bounds__(256) void k_gemm1_mfma(const float* __restrict__ x,
                                                    const short* __restrict__ W1t,
                                                    const float* __restrict__ dinv,
                                                    unsigned short* __restrict__ h1b) {
    __shared__ short As[64 * 40];    // row stride 40 bf16 (80 B): 2-way banks, free
    __shared__ short Bs[128 * 40];
    __shared__ float Ds[64];
    const int tid = threadIdx.x;
    const int row0 = blockIdx.x * 64;
    const int w = tid >> 6, l = tid & 63;
    const int l15 = l & 15, q = l >> 4;
    const int ar = tid >> 2;             // 0..63
    const int ak = (tid & 3) * 8;        // 0,8,16,24
    const int bn = tid >> 1;             // 0..127
    const int bk = (tid & 1) * 16;

    if (tid < 64) {
        int r = row0 + tid;
        Ds[tid] = (r < N_NODES) ? dinv[r] : 0.f;
    }

    floatx4 acc[4][2];
#pragma unroll
    for (int mt = 0; mt < 4; ++mt)
#pragma unroll
        for (int nt = 0; nt < 2; ++nt) acc[mt][nt] = (floatx4)0.f;

    const bool arow_ok = (row0 + ar) < N_NODES;
    const float* xp = x + (size_t)(row0 + ar) * F_IN;

    for (int k0 = 0; k0 < F_IN; k0 += 32) {
        bf16x8 av;
        if (arow_ok) {
            float4 f0 = *(const float4*)(xp + k0 + ak);
            float4 f1 = *(const float4*)(xp + k0 + ak + 4);
            av[0] = (short)f2bf(f0.x); av[1] = (short)f2bf(f0.y);
            av[2] = (short)f2bf(f0.z); av[3] = (short)f2bf(f0.w);
            av[4] = (short)f2bf(f1.x); av[5] = (short)f2bf(f1.y);
            av[6] = (short)f2bf(f1.z); av[7] = (short)f2bf(f1.w);
        } else {
            av = (bf16x8)0;
        }
        *(bf16x8*)&As[ar * 40 + ak] = av;
        *(bf16x8*)&Bs[bn * 40 + bk]     = *(const bf16x8*)&W1t[bn * 256 + k0 + bk];
        *(bf16x8*)&Bs[bn * 40 + bk + 8] = *(const bf16x8*)&W1t[bn * 256 + k0 + bk + 8];
        __syncthreads();

        bf16x8 af[4], bfr[2];
#pragma unroll
        for (int mt = 0; mt < 4; ++mt)
            af[mt] = *(const bf16x8*)&As[(mt * 16 + l15) * 40 + q * 8];
#pragma unroll
        for (int nt = 0; nt < 2; ++nt)
            bfr[nt] = *(const bf16x8*)&Bs[(w * 32 + nt * 16 + l15) * 40 + q * 8];
#pragma unroll
        for (int mt = 0; mt < 4; ++mt)
#pragma unroll
            for (int nt = 0; nt < 2; ++nt)
                acc[mt][nt] = __builtin_amdgcn_mfma_f32_16x16x32_bf16(af[mt], bfr[nt], acc[mt][nt], 0, 0, 0);
        __syncthreads();
    }
#pragma unroll
    for (int mt = 0; mt < 4; ++mt) {
#pragma unroll
        for (int nt = 0; nt < 2; ++nt) {
            int col = w * 32 + nt * 16 + l15;
#pragma unroll
            for (int r = 0; r < 4; ++r) {
                int rl = mt * 16 + q * 4 + r;
                int row = row0 + rl;
                if (row < N_NODES)
                    h1b[(size_t)row * F_H + col] = f2bf(acc[mt][nt][r] * Ds[rl]);
            }
        }
    }
}

// ---- SpMM1: wave per node, lane l = feature pair [2l,2l+1]; bf16 gather ----
// agg1 = relu( dinv[d] * (h1s[d] + sum h1s[src]) + b1 ), h1s pre-scaled by dinv
__global__ __launch_bounds__(256) void k_spmm1(const int* __restrict__ rowptr,
                                               const int* __restrict__ csr_src,
                                               const unsigned int* __restrict__ h1p,  // h1b as dwords
                                               const float* __restrict__ dinv,
                                               const float* __restrict__ b1,
                                               unsigned int* __restrict__ agg1p) {   // agg1b as dwords
    int wave = threadIdx.x >> 6;
    int node = blockIdx.x * 4 + wave;
    int l = threadIdx.x & 63;
    if (node >= N_NODES) return;
    int beg = rowptr[node], end = rowptr[node + 1];
    float d = dinv[node];
    unsigned int su = h1p[(size_t)node * 64 + l];
    float aL0 = bf_lo(su), aH0 = bf_hi(su);   // self loop (pre-scaled)
    float aL1 = 0.f, aH1 = 0.f, aL2 = 0.f, aH2 = 0.f, aL3 = 0.f, aH3 = 0.f;
    int i = beg;
    for (; i + 3 < end; i += 4) {
        int s0 = csr_src[i], s1 = csr_src[i + 1], s2 = csr_src[i + 2], s3 = csr_src[i + 3];
        unsigned int u0 = h1p[(size_t)s0 * 64 + l];
        unsigned int u1 = h1p[(size_t)s1 * 64 + l];
        unsigned int u2 = h1p[(size_t)s2 * 64 + l];
        unsigned int u3 = h1p[(size_t)s3 * 64 + l];
        aL0 += bf_lo(u0); aH0 += bf_hi(u0);
        aL1 += bf_lo(u1); aH1 += bf_hi(u1);
        aL2 += bf_lo(u2); aH2 += bf_hi(u2);
        aL3 += bf_lo(u3); aH3 += bf_hi(u3);
    }
    for (; i < end; ++i) {
        unsigned int u0 = h1p[(size_t)csr_src[i] * 64 + l];
        aL0 += bf_lo(u0); aH0 += bf_hi(u0);
    }
    float vL = fmaf((aL0 + aL1) + (aL2 + aL3), d, b1[2 * l]);
    float vH = fmaf((aH0 + aH1) + (aH2 + aH3), d, b1[2 * l + 1]);
    vL = vL > 0.f ? vL : 0.f;
    vH = vH > 0.f ? vH : 0.f;
    agg1p[(size_t)node * 64 + l] = ((unsigned int)f2bf(vH) << 16) | f2bf(vL);
}

// ---- GEMM2 (MFMA bf16): h2b[N,40](bf16) = dinv[row] * (agg1b[N,128] @ W2) ----
__global__ __launch_bounds__(256) void k_gemm2_mfma(const unsigned short* __restrict__ agg1b,
                                                    const short* __restrict__ W2t,
                                                    const float* __restrict__ dinv,
                                                    unsigned short* __restrict__ h2b) {
    __shared__ short As[128 * 40];     // 10 KB
    __shared__ short Bs[48 * 136];     // 12.75 KB
    __shared__ float Ds[128];
    const int tid = threadIdx.x;
    const int row0 = blockIdx.x * 128;
    const int w = tid >> 6, l = tid & 63;
    const int l15 = l & 15, q = l >> 4;
    const int ar = tid >> 1;             // 0..127
    const int ak = (tid & 1) * 16;

#pragma unroll
    for (int i = 0; i < 3; ++i) {
        int c = tid * 3 + i;             // 0..767 chunks of 8 bf16
        int n = c >> 4, koff = (c & 15) * 8;
        *(bf16x8*)&Bs[n * 136 + koff] = *(const bf16x8*)&W2t[n * 128 + koff];
    }
    if (tid < 128) {
        int r = row0 + tid;
        Ds[tid] = (r < N_NODES) ? dinv[r] : 0.f;
    }

    floatx4 acc[2][3];
#pragma unroll
    for (int a = 0; a < 2; ++a)
#pragma unroll
        for (int nt = 0; nt < 3; ++nt) acc[a][nt] = (floatx4)0.f;

    const bool arow_ok = (row0 + ar) < N_NODES;
    const unsigned short* ap = agg1b + (size_t)(row0 + ar) * F_H;

    for (int k0 = 0; k0 < F_H; k0 += 32) {
        bf16x8 a0, a1;
        if (arow_ok) {
            a0 = *(const bf16x8*)(ap + k0 + ak);
            a1 = *(const bf16x8*)(ap + k0 + ak + 8);
        } else {
            a0 = (bf16x8)0; a1 = (bf16x8)0;
        }
        *(bf16x8*)&As[ar * 40 + ak]     = a0;
        *(bf16x8*)&As[ar * 40 + ak + 8] = a1;
        __syncthreads();

        bf16x8 af[2], bfr[3];
#pragma unroll
        for (int a = 0; a < 2; ++a)
            af[a] = *(const bf16x8*)&As[((w * 2 + a) * 16 + l15) * 40 + q * 8];
#pragma unroll
        for (int nt = 0; nt < 3; ++nt)
            bfr[nt] = *(const bf16x8*)&Bs[(nt * 16 + l15) * 136 + k0 + q * 8];
#pragma unroll
        for (int a = 0; a < 2; ++a)
#pragma unroll
            for (int nt = 0; nt < 3; ++nt)
                acc[a][nt] = __builtin_amdgcn_mfma_f32_16x16x32_bf16(af[a], bfr[nt], acc[a][nt], 0, 0, 0);
        __syncthreads();
    }
#pragma unroll
    for (int a = 0; a < 2; ++a) {
#pragma unroll
        for (int nt = 0; nt < 3; ++nt) {
            int col = nt * 16 + l15;
#pragma unroll
            for (int r = 0; r < 4; ++r) {
                int rl = (w * 2 + a) * 16 + q * 4 + r;
                int row = row0 + rl;
                if (row < N_NODES && col < F_OUT)
                    h2b[(size_t)row * F_OUT + col] = f2bf(acc[a][nt][r] * Ds[rl]);
            }
        }
    }
}

// ---- SpMM2 (bf16 gather) + b2 + log_softmax, wave per node ----
__global__ __launch_bounds__(256) void k_spmm2_lsm(const int* __restrict__ rowptr,
                                                   const int* __restrict__ csr_src,
                                                   const unsigned short* __restrict__ h2b,
                                                   const float* __restrict__ dinv,
                                                   const float* __restrict__ b2,
                                                   float* __restrict__ out) {
    int wave = threadIdx.x >> 6;
    int node = blockIdx.x * 4 + wave;
    int lane = threadIdx.x & 63;
    if (node >= N_NODES) return;
    int beg = rowptr[node], end = rowptr[node + 1];
    float d = dinv[node];
    const bool act = lane < F_OUT;
    float a0 = 0.f, a1 = 0.f, a2 = 0.f, a3 = 0.f;
    if (act) a0 = bf2f(h2b[(size_t)node * F_OUT + lane]);   // self loop (pre-scaled)
    int i = beg;
    for (; i + 3 < end; i += 4) {
        int s0 = csr_src[i], s1 = csr_src[i + 1], s2 = csr_src[i + 2], s3 = csr_src[i + 3];
        if (act) {
            a0 += bf2f(h2b[(size_t)s0 * F_OUT + lane]);
            a1 += bf2f(h2b[(size_t)s1 * F_OUT + lane]);
            a2 += bf2f(h2b[(size_t)s2 * F_OUT + lane]);
            a3 += bf2f(h2b[(size_t)s3 * F_OUT + lane]);
        }
    }
    for (; i < end; ++i) {
        if (act) a0 += bf2f(h2b[(size_t)csr_src[i] * F_OUT + lane]);
    }
    float v = act ? fmaf((a0 + a1) + (a2 + a3), d, b2[lane]) : -INFINITY;
    float m = v;
#pragma unroll
    for (int o = 32; o > 0; o >>= 1) m = fmaxf(m, __shfl_xor(m, o, 64));
    float ev = act ? expf(v - m) : 0.f;
    float ssum = ev;
#pragma unroll
    for (int o = 32; o > 0; o >>= 1) ssum += __shfl_xor(ssum, o, 64);
    if (act) out[(size_t)node * F_OUT + lane] = v - m - logf(ssum);
}

extern "C" void kernel_launch(void* const* d_in, const int* in_sizes, int n_in,
                              void* d_out, int out_size, void* d_ws, size_t ws_size,
                              hipStream_t stream) {
    const float* x = (const float*)d_in[0];
    const int* eidx = (const int*)d_in[1];   // int32 from harness
    const float* W1 = (const float*)d_in[2];
    const float* b1 = (const float*)d_in[3];
    const float* W2 = (const float*)d_in[4];
    const float* b2 = (const float*)d_in[5];
    float* out = (float*)d_out;

    char* ws = (char*)d_ws;
    int*   degi      = (int*)  (ws);                 // 100000 ints
    int*   chunkSums = (int*)  (ws + 400000);        // 128
    int*   rowptr    = (int*)  (ws + 400512);        // 100001
    int*   cursor    = (int*)  (ws + 800528);        // 100000
    int*   csr_src   = (int*)  (ws + 1200528);       // 1.6M ints
    float* dinv      = (float*)(ws + 7600528);       // 100000
    short* W1t       = (short*)(ws + 8000528);       // 32768 bf16
    short* W2t       = (short*)(ws + 8066064);       // 6144 bf16
    unsigned short* h1b   = (unsigned short*)(ws + 8078352);   // 12.8M bf16 (25.6 MB)
    unsigned short* agg1b = (unsigned short*)(ws + 33678352);  // 12.8M bf16 (25.6 MB)
    unsigned short* h2b   = (unsigned short*)(ws + 59278352);  // 4M bf16 (8 MB)

    k_zero<<<(N_NODES + 255) / 256, 256, 0, stream>>>(degi, N_NODES);
    k_deg<<<(N_EDGES + 255) / 256, 256, 0, stream>>>(eidx, degi);
    k_dinv<<<(N_NODES + 255) / 256, 256, 0, stream>>>(degi, dinv);
    k_chunk_sums<<<NCHUNK, 256, 0, stream>>>(degi, chunkSums);
    k_scan_sums<<<1, 128, 0, stream>>>(chunkSums);
    k_scan_final<<<NCHUNK, 256, 0, stream>>>(degi, chunkSums, rowptr, cursor);
    k_fill<<<(N_EDGES + 255) / 256, 256, 0, stream>>>(eidx, cursor, csr_src);

    k_cvt_w1<<<128, 256, 0, stream>>>(W1, W1t);
    k_cvt_w2<<<24, 256, 0, stream>>>(W2, W2t);

    k_gemm1_mfma<<<(N_NODES + 63) / 64, 256, 0, stream>>>(x, W1t, dinv, h1b);
    k_spmm1<<<(N_NODES + 3) / 4, 256, 0, stream>>>(rowptr, csr_src,
                                                   (const unsigned int*)h1b, dinv, b1,
                                                   (unsigned int*)agg1b);
    k_gemm2_mfma<<<(N_NODES + 127) / 128, 256, 0, stream>>>(agg1b, W2t, dinv, h2b);
    k_spmm2_lsm<<<(N_NODES + 3) / 4, 256, 0, stream>>>(rowptr, csr_src, h2b, dinv, b2, out);
}

// Round 7
// 494.011 us; speedup vs baseline: 1.1173x; 1.1173x over previous
//
#include <hip/hip_runtime.h>
#include <math.h>

#define N_NODES 100000
#define N_EDGES 1600000
#define F_IN 256
#define F_H 128
#define F_OUT 40
#define SCAN_CHUNK 1024
#define NCHUNK ((N_NODES + SCAN_CHUNK - 1) / SCAN_CHUNK)   // 98

typedef __attribute__((ext_vector_type(8))) short bf16x8;
typedef __attribute__((ext_vector_type(4))) float floatx4;

__device__ __forceinline__ unsigned short f2bf(float f) {
    unsigned int u = __float_as_uint(f);
    u += 0x7fffu + ((u >> 16) & 1u);          // RNE (finite inputs)
    return (unsigned short)(u >> 16);
}
__device__ __forceinline__ float bf_lo(unsigned int u) { return __uint_as_float(u << 16); }
__device__ __forceinline__ float bf_hi(unsigned int u) { return __uint_as_float(u & 0xffff0000u); }
__device__ __forceinline__ float bf2f(unsigned short s) { return __uint_as_float(((unsigned int)s) << 16); }

// ---- zero int array ----
__global__ void k_zero(int* p, int n) {
    int i = blockIdx.x * blockDim.x + threadIdx.x;
    if (i < n) p[i] = 0;
}

// ---- int degree count over dst ----
__global__ void k_deg(const int* __restrict__ eidx, int* degi) {
    int e = blockIdx.x * blockDim.x + threadIdx.x;
    if (e < N_EDGES) atomicAdd(&degi[eidx[N_EDGES + e]], 1);
}

// ---- dinv = rsqrt(deg + 1 [self-loop]) ----
__global__ void k_dinv(const int* __restrict__ degi, float* __restrict__ dinv) {
    int i = blockIdx.x * blockDim.x + threadIdx.x;
    if (i < N_NODES) dinv[i] = rsqrtf((float)degi[i] + 1.0f);
}

// ---- scan level 1 ----
__global__ __launch_bounds__(256) void k_chunk_sums(const int* __restrict__ degi,
                                                    int* __restrict__ chunkSums) {
    __shared__ int lds[256];
    int b = blockIdx.x, t = threadIdx.x;
    int base = b * SCAN_CHUNK;
    int s = 0;
#pragma unroll
    for (int j = 0; j < 4; ++j) {
        int i = base + j * 256 + t;
        if (i < N_NODES) s += degi[i];
    }
    lds[t] = s;
    __syncthreads();
    for (int off = 128; off > 0; off >>= 1) {
        if (t < off) lds[t] += lds[t + off];
        __syncthreads();
    }
    if (t == 0) chunkSums[b] = lds[0];
}

// ---- scan level 2 ----
__global__ __launch_bounds__(128) void k_scan_sums(int* chunkSums) {
    __shared__ int lds[NCHUNK];
    int t = threadIdx.x;
    if (t < NCHUNK) lds[t] = chunkSums[t];
    __syncthreads();
    if (t == 0) {
        int run = 0;
        for (int i = 0; i < NCHUNK; ++i) { int c = lds[i]; lds[i] = run; run += c; }
    }
    __syncthreads();
    if (t < NCHUNK) chunkSums[t] = lds[t];
}

// ---- scan level 3 ----
__global__ __launch_bounds__(256) void k_scan_final(const int* __restrict__ degi,
                                                    const int* __restrict__ chunkOff,
                                                    int* __restrict__ rowptr,
                                                    int* __restrict__ cursor) {
    __shared__ int tsum[256];
    int b = blockIdx.x, t = threadIdx.x;
    int base = b * SCAN_CHUNK;
    int v[4];
    int s = 0;
#pragma unroll
    for (int j = 0; j < 4; ++j) {
        int i = base + t * 4 + j;
        v[j] = (i < N_NODES) ? degi[i] : 0;
        s += v[j];
    }
    tsum[t] = s;
    __syncthreads();
    for (int off = 1; off < 256; off <<= 1) {
        int val = 0;
        if (t >= off) val = tsum[t - off];
        __syncthreads();
        if (t >= off) tsum[t] += val;
        __syncthreads();
    }
    int run = chunkOff[b] + ((t == 0) ? 0 : tsum[t - 1]);
#pragma unroll
    for (int j = 0; j < 4; ++j) {
        int i = base + t * 4 + j;
        if (i < N_NODES) { rowptr[i] = run; cursor[i] = run; }
        run += v[j];
    }
    if (b == 0 && t == 0) rowptr[N_NODES] = N_EDGES;
}

// ---- CSR fill, XCD-bucketed: blockIdx&7 -> dst bucket of 12500 nodes ----
// All csr_src/cursor lines of a bucket are touched (heuristically) by one XCD
// -> single-L2 residency, ~1x line writeback instead of ~16x.
__global__ __launch_bounds__(256) void k_fill_bucket(const int* __restrict__ eidx,
                                                     int* cursor, int* __restrict__ csr_src) {
    const int bucket = blockIdx.x & 7;
    const int chunk = blockIdx.x >> 3;
    const int nchunks = gridDim.x >> 3;
    const int lo = bucket * (N_NODES / 8);
    const int hi = lo + (N_NODES / 8);
    for (int e = chunk * 256 + threadIdx.x; e < N_EDGES; e += nchunks * 256) {
        int d = eidx[N_EDGES + e];
        if (d >= lo && d < hi) {
            int s = eidx[e];
            int pos = atomicAdd(&cursor[d], 1);
            csr_src[pos] = s;
        }
    }
}

// ---- W1 [256][128] fp32 -> W1t [128][256] bf16 ----
__global__ void k_cvt_w1(const float* __restrict__ W1, short* __restrict__ W1t) {
    int idx = blockIdx.x * blockDim.x + threadIdx.x;   // 32768
    int n = idx >> 8, k = idx & 255;
    W1t[n * 256 + k] = (short)f2bf(W1[k * 128 + n]);
}

// ---- W2 [128][40] fp32 -> W2t [48][128] bf16 (zero-padded cols 40..47) ----
__global__ void k_cvt_w2(const float* __restrict__ W2, short* __restrict__ W2t) {
    int idx = blockIdx.x * blockDim.x + threadIdx.x;   // 6144
    if (idx >= 48 * 128) return;
    int n = idx >> 7, k = idx & 127;
    float v = (n < F_OUT) ? W2[k * F_OUT + n] : 0.f;
    W2t[n * 128 + k] = (short)f2bf(v);
}

// ---- GEMM1 (MFMA bf16): h1b[N,128](bf16) = dinv[row] * (x[N,256] @ W1) ----
__global__ __launch_bounds__(256) void k_gemm1_mfma(const float* __restrict__ x,
                                                    const short* __restrict__ W1t,
                                                    const float* __restrict__ dinv,
                                                    unsigned short* __restrict__ h1b) {
    __shared__ short As[64 * 40];    // row stride 40 bf16 (80 B): 2-way banks, free
    __shared__ short Bs[128 * 40];
    __shared__ float Ds[64];
    const int tid = threadIdx.x;
    const int row0 = blockIdx.x * 64;
    const int w = tid >> 6, l = tid & 63;
    const int l15 = l & 15, q = l >> 4;
    const int ar = tid >> 2;             // 0..63
    const int ak = (tid & 3) * 8;        // 0,8,16,24
    const int bn = tid >> 1;             // 0..127
    const int bk = (tid & 1) * 16;

    if (tid < 64) {
        int r = row0 + tid;
        Ds[tid] = (r < N_NODES) ? dinv[r] : 0.f;
    }

    floatx4 acc[4][2];
#pragma unroll
    for (int mt = 0; mt < 4; ++mt)
#pragma unroll
        for (int nt = 0; nt < 2; ++nt) acc[mt][nt] = (floatx4)0.f;

    const bool arow_ok = (row0 + ar) < N_NODES;
    const float* xp = x + (size_t)(row0 + ar) * F_IN;

    for (int k0 = 0; k0 < F_IN; k0 += 32) {
        bf16x8 av;
        if (arow_ok) {
            float4 f0 = *(const float4*)(xp + k0 + ak);
            float4 f1 = *(const float4*)(xp + k0 + ak + 4);
            av[0] = (short)f2bf(f0.x); av[1] = (short)f2bf(f0.y);
            av[2] = (short)f2bf(f0.z); av[3] = (short)f2bf(f0.w);
            av[4] = (short)f2bf(f1.x); av[5] = (short)f2bf(f1.y);
            av[6] = (short)f2bf(f1.z); av[7] = (short)f2bf(f1.w);
        } else {
            av = (bf16x8)0;
        }
        *(bf16x8*)&As[ar * 40 + ak] = av;
        *(bf16x8*)&Bs[bn * 40 + bk]     = *(const bf16x8*)&W1t[bn * 256 + k0 + bk];
        *(bf16x8*)&Bs[bn * 40 + bk + 8] = *(const bf16x8*)&W1t[bn * 256 + k0 + bk + 8];
        __syncthreads();

        bf16x8 af[4], bfr[2];
#pragma unroll
        for (int mt = 0; mt < 4; ++mt)
            af[mt] = *(const bf16x8*)&As[(mt * 16 + l15) * 40 + q * 8];
#pragma unroll
        for (int nt = 0; nt < 2; ++nt)
            bfr[nt] = *(const bf16x8*)&Bs[(w * 32 + nt * 16 + l15) * 40 + q * 8];
#pragma unroll
        for (int mt = 0; mt < 4; ++mt)
#pragma unroll
            for (int nt = 0; nt < 2; ++nt)
                acc[mt][nt] = __builtin_amdgcn_mfma_f32_16x16x32_bf16(af[mt], bfr[nt], acc[mt][nt], 0, 0, 0);
        __syncthreads();
    }
#pragma unroll
    for (int mt = 0; mt < 4; ++mt) {
#pragma unroll
        for (int nt = 0; nt < 2; ++nt) {
            int col = w * 32 + nt * 16 + l15;
#pragma unroll
            for (int r = 0; r < 4; ++r) {
                int rl = mt * 16 + q * 4 + r;
                int row = row0 + rl;
                if (row < N_NODES)
                    h1b[(size_t)row * F_H + col] = f2bf(acc[mt][nt][r] * Ds[rl]);
            }
        }
    }
}

// ---- SpMM1: wave per node, lane l = feature pair [2l,2l+1]; bf16 gather ----
__global__ __launch_bounds__(256) void k_spmm1(const int* __restrict__ rowptr,
                                               const int* __restrict__ csr_src,
                                               const unsigned int* __restrict__ h1p,
                                               const float* __restrict__ dinv,
                                               const float* __restrict__ b1,
                                               unsigned int* __restrict__ agg1p) {
    int wave = threadIdx.x >> 6;
    int node = blockIdx.x * 4 + wave;
    int l = threadIdx.x & 63;
    if (node >= N_NODES) return;
    int beg = rowptr[node], end = rowptr[node + 1];
    float d = dinv[node];
    unsigned int su = h1p[(size_t)node * 64 + l];
    float aL0 = bf_lo(su), aH0 = bf_hi(su);   // self loop (pre-scaled)
    float aL1 = 0.f, aH1 = 0.f, aL2 = 0.f, aH2 = 0.f, aL3 = 0.f, aH3 = 0.f;
    int i = beg;
    for (; i + 3 < end; i += 4) {
        int s0 = csr_src[i], s1 = csr_src[i + 1], s2 = csr_src[i + 2], s3 = csr_src[i + 3];
        unsigned int u0 = h1p[(size_t)s0 * 64 + l];
        unsigned int u1 = h1p[(size_t)s1 * 64 + l];
        unsigned int u2 = h1p[(size_t)s2 * 64 + l];
        unsigned int u3 = h1p[(size_t)s3 * 64 + l];
        aL0 += bf_lo(u0); aH0 += bf_hi(u0);
        aL1 += bf_lo(u1); aH1 += bf_hi(u1);
        aL2 += bf_lo(u2); aH2 += bf_hi(u2);
        aL3 += bf_lo(u3); aH3 += bf_hi(u3);
    }
    for (; i < end; ++i) {
        unsigned int u0 = h1p[(size_t)csr_src[i] * 64 + l];
        aL0 += bf_lo(u0); aH0 += bf_hi(u0);
    }
    float vL = fmaf((aL0 + aL1) + (aL2 + aL3), d, b1[2 * l]);
    float vH = fmaf((aH0 + aH1) + (aH2 + aH3), d, b1[2 * l + 1]);
    vL = vL > 0.f ? vL : 0.f;
    vH = vH > 0.f ? vH : 0.f;
    agg1p[(size_t)node * 64 + l] = ((unsigned int)f2bf(vH) << 16) | f2bf(vL);
}

// ---- GEMM2 (MFMA bf16): h2b[N,40](bf16) = dinv[row] * (agg1b[N,128] @ W2) ----
__global__ __launch_bounds__(256) void k_gemm2_mfma(const unsigned short* __restrict__ agg1b,
                                                    const short* __restrict__ W2t,
                                                    const float* __restrict__ dinv,
                                                    unsigned short* __restrict__ h2b) {
    __shared__ short As[128 * 40];     // 10 KB
    __shared__ short Bs[48 * 136];     // 12.75 KB
    __shared__ float Ds[128];
    const int tid = threadIdx.x;
    const int row0 = blockIdx.x * 128;
    const int w = tid >> 6, l = tid & 63;
    const int l15 = l & 15, q = l >> 4;
    const int ar = tid >> 1;             // 0..127
    const int ak = (tid & 1) * 16;

#pragma unroll
    for (int i = 0; i < 3; ++i) {
        int c = tid * 3 + i;             // 0..767 chunks of 8 bf16
        int n = c >> 4, koff = (c & 15) * 8;
        *(bf16x8*)&Bs[n * 136 + koff] = *(const bf16x8*)&W2t[n * 128 + koff];
    }
    if (tid < 128) {
        int r = row0 + tid;
        Ds[tid] = (r < N_NODES) ? dinv[r] : 0.f;
    }

    floatx4 acc[2][3];
#pragma unroll
    for (int a = 0; a < 2; ++a)
#pragma unroll
        for (int nt = 0; nt < 3; ++nt) acc[a][nt] = (floatx4)0.f;

    const bool arow_ok = (row0 + ar) < N_NODES;
    const unsigned short* ap = agg1b + (size_t)(row0 + ar) * F_H;

    for (int k0 = 0; k0 < F_H; k0 += 32) {
        bf16x8 a0, a1;
        if (arow_ok) {
            a0 = *(const bf16x8*)(ap + k0 + ak);
            a1 = *(const bf16x8*)(ap + k0 + ak + 8);
        } else {
            a0 = (bf16x8)0; a1 = (bf16x8)0;
        }
        *(bf16x8*)&As[ar * 40 + ak]     = a0;
        *(bf16x8*)&As[ar * 40 + ak + 8] = a1;
        __syncthreads();

        bf16x8 af[2], bfr[3];
#pragma unroll
        for (int a = 0; a < 2; ++a)
            af[a] = *(const bf16x8*)&As[((w * 2 + a) * 16 + l15) * 40 + q * 8];
#pragma unroll
        for (int nt = 0; nt < 3; ++nt)
            bfr[nt] = *(const bf16x8*)&Bs[(nt * 16 + l15) * 136 + k0 + q * 8];
#pragma unroll
        for (int a = 0; a < 2; ++a)
#pragma unroll
            for (int nt = 0; nt < 3; ++nt)
                acc[a][nt] = __builtin_amdgcn_mfma_f32_16x16x32_bf16(af[a], bfr[nt], acc[a][nt], 0, 0, 0);
        __syncthreads();
    }
#pragma unroll
    for (int a = 0; a < 2; ++a) {
#pragma unroll
        for (int nt = 0; nt < 3; ++nt) {
            int col = nt * 16 + l15;
#pragma unroll
            for (int r = 0; r < 4; ++r) {
                int rl = (w * 2 + a) * 16 + q * 4 + r;
                int row = row0 + rl;
                if (row < N_NODES && col < F_OUT)
                    h2b[(size_t)row * F_OUT + col] = f2bf(acc[a][nt][r] * Ds[rl]);
            }
        }
    }
}

// ---- SpMM2 (bf16 gather) + b2 + log_softmax, wave per node ----
__global__ __launch_bounds__(256) void k_spmm2_lsm(const int* __restrict__ rowptr,
                                                   const int* __restrict__ csr_src,
                                                   const unsigned short* __restrict__ h2b,
                                                   const float* __restrict__ dinv,
                                                   const float* __restrict__ b2,
                                                   float* __restrict__ out) {
    int wave = threadIdx.x >> 6;
    int node = blockIdx.x * 4 + wave;
    int lane = threadIdx.x & 63;
    if (node >= N_NODES) return;
    int beg = rowptr[node], end = rowptr[node + 1];
    float d = dinv[node];
    const bool act = lane < F_OUT;
    float a0 = 0.f, a1 = 0.f, a2 = 0.f, a3 = 0.f;
    if (act) a0 = bf2f(h2b[(size_t)node * F_OUT + lane]);   // self loop (pre-scaled)
    int i = beg;
    for (; i + 3 < end; i += 4) {
        int s0 = csr_src[i], s1 = csr_src[i + 1], s2 = csr_src[i + 2], s3 = csr_src[i + 3];
        if (act) {
            a0 += bf2f(h2b[(size_t)s0 * F_OUT + lane]);
            a1 += bf2f(h2b[(size_t)s1 * F_OUT + lane]);
            a2 += bf2f(h2b[(size_t)s2 * F_OUT + lane]);
            a3 += bf2f(h2b[(size_t)s3 * F_OUT + lane]);
        }
    }
    for (; i < end; ++i) {
        if (act) a0 += bf2f(h2b[(size_t)csr_src[i] * F_OUT + lane]);
    }
    float v = act ? fmaf((a0 + a1) + (a2 + a3), d, b2[lane]) : -INFINITY;
    float m = v;
#pragma unroll
    for (int o = 32; o > 0; o >>= 1) m = fmaxf(m, __shfl_xor(m, o, 64));
    float ev = act ? expf(v - m) : 0.f;
    float ssum = ev;
#pragma unroll
    for (int o = 32; o > 0; o >>= 1) ssum += __shfl_xor(ssum, o, 64);
    if (act) out[(size_t)node * F_OUT + lane] = v - m - logf(ssum);
}

extern "C" void kernel_launch(void* const* d_in, const int* in_sizes, int n_in,
                              void* d_out, int out_size, void* d_ws, size_t ws_size,
                              hipStream_t stream) {
    const float* x = (const float*)d_in[0];
    const int* eidx = (const int*)d_in[1];   // int32 from harness
    const float* W1 = (const float*)d_in[2];
    const float* b1 = (const float*)d_in[3];
    const float* W2 = (const float*)d_in[4];
    const float* b2 = (const float*)d_in[5];
    float* out = (float*)d_out;

    char* ws = (char*)d_ws;
    int*   degi      = (int*)  (ws);                 // 100000 ints
    int*   chunkSums = (int*)  (ws + 400000);        // 128
    int*   rowptr    = (int*)  (ws + 400512);        // 100001
    int*   cursor    = (int*)  (ws + 800528);        // 100000
    int*   csr_src   = (int*)  (ws + 1200528);       // 1.6M ints
    float* dinv      = (float*)(ws + 7600528);       // 100000
    short* W1t       = (short*)(ws + 8000528);       // 32768 bf16
    short* W2t       = (short*)(ws + 8066064);       // 6144 bf16
    unsigned short* h1b   = (unsigned short*)(ws + 8078352);   // 12.8M bf16 (25.6 MB)
    unsigned short* agg1b = (unsigned short*)(ws + 33678352);  // 12.8M bf16 (25.6 MB)
    unsigned short* h2b   = (unsigned short*)(ws + 59278352);  // 4M bf16 (8 MB)

    k_zero<<<(N_NODES + 255) / 256, 256, 0, stream>>>(degi, N_NODES);
    k_deg<<<(N_EDGES + 255) / 256, 256, 0, stream>>>(eidx, degi);
    k_dinv<<<(N_NODES + 255) / 256, 256, 0, stream>>>(degi, dinv);
    k_chunk_sums<<<NCHUNK, 256, 0, stream>>>(degi, chunkSums);
    k_scan_sums<<<1, 128, 0, stream>>>(chunkSums);
    k_scan_final<<<NCHUNK, 256, 0, stream>>>(degi, chunkSums, rowptr, cursor);
    k_fill_bucket<<<4096, 256, 0, stream>>>(eidx, cursor, csr_src);

    k_cvt_w1<<<128, 256, 0, stream>>>(W1, W1t);
    k_cvt_w2<<<24, 256, 0, stream>>>(W2, W2t);

    k_gemm1_mfma<<<(N_NODES + 63) / 64, 256, 0, stream>>>(x, W1t, dinv, h1b);
    k_spmm1<<<(N_NODES + 3) / 4, 256, 0, stream>>>(rowptr, csr_src,
                                                   (const unsigned int*)h1b, dinv, b1,
                                                   (unsigned int*)agg1b);
    k_gemm2_mfma<<<(N_NODES + 127) / 128, 256, 0, stream>>>(agg1b, W2t, dinv, h2b);
    k_spmm2_lsm<<<(N_NODES + 3) / 4, 256, 0, stream>>>(rowptr, csr_src, h2b, dinv, b2, out);
}

// Round 8
// 470.059 us; speedup vs baseline: 1.1743x; 1.0510x over previous
//
#include <hip/hip_runtime.h>
#include <hip/hip_fp8.h>
#include <math.h>

#define N_NODES 100000
#define N_EDGES 1600000
#define F_IN 256
#define F_H 128
#define F_OUT 40
#define SCAN_CHUNK 1024
#define NCHUNK ((N_NODES + SCAN_CHUNK - 1) / SCAN_CHUNK)   // 98

typedef __attribute__((ext_vector_type(8))) short bf16x8;
typedef __attribute__((ext_vector_type(4))) float floatx4;
typedef __attribute__((ext_vector_type(2))) float floatx2;

__device__ __forceinline__ unsigned short f2bf(float f) {
    unsigned int u = __float_as_uint(f);
    u += 0x7fffu + ((u >> 16) & 1u);          // RNE (finite inputs)
    return (unsigned short)(u >> 16);
}
__device__ __forceinline__ float bf_lo(unsigned int u) { return __uint_as_float(u << 16); }
__device__ __forceinline__ float bf_hi(unsigned int u) { return __uint_as_float(u & 0xffff0000u); }
__device__ __forceinline__ float bf2f(unsigned short s) { return __uint_as_float(((unsigned int)s) << 16); }

// ---- fp8 e4m3 (OCP) encode/decode, native cvt when available ----
#if defined(__has_builtin)
#if __has_builtin(__builtin_amdgcn_cvt_pk_fp8_f32)
#define HAVE_PK_ENC 1
#endif
#if __has_builtin(__builtin_amdgcn_cvt_pk_f32_fp8)
#define HAVE_PK_DEC 1
#endif
#if __has_builtin(__builtin_amdgcn_cvt_f32_fp8)
#define HAVE_SC_DEC 1
#endif
#endif

__device__ __forceinline__ unsigned char f2f8(float f) {
#ifdef HAVE_PK_ENC
    int r = __builtin_amdgcn_cvt_pk_fp8_f32(f, f, 0, false);
    return (unsigned char)(r & 0xff);
#else
    __hip_fp8_e4m3 t(f);
    return (unsigned char)t.__x;
#endif
}
__device__ __forceinline__ float f82f(unsigned char b) {
#ifdef HAVE_SC_DEC
    return __builtin_amdgcn_cvt_f32_fp8((int)b, 0);
#else
    __hip_fp8_e4m3 t; t.__x = (__hip_fp8_storage_t)b;
    return (float)t;
#endif
}
__device__ __forceinline__ floatx2 f8x2tof(unsigned short u) {
#ifdef HAVE_PK_DEC
    return __builtin_amdgcn_cvt_pk_f32_fp8((int)u, false);
#else
    floatx2 r;
    r.x = f82f((unsigned char)(u & 0xff));
    r.y = f82f((unsigned char)(u >> 8));
    return r;
#endif
}

// ---- zero int array ----
__global__ void k_zero(int* p, int n) {
    int i = blockIdx.x * blockDim.x + threadIdx.x;
    if (i < n) p[i] = 0;
}

// ---- int degree count over dst ----
__global__ void k_deg(const int* __restrict__ eidx, int* degi) {
    int e = blockIdx.x * blockDim.x + threadIdx.x;
    if (e < N_EDGES) atomicAdd(&degi[eidx[N_EDGES + e]], 1);
}

// ---- scan level 1 ----
__global__ __launch_bounds__(256) void k_chunk_sums(const int* __restrict__ degi,
                                                    int* __restrict__ chunkSums) {
    __shared__ int lds[256];
    int b = blockIdx.x, t = threadIdx.x;
    int base = b * SCAN_CHUNK;
    int s = 0;
#pragma unroll
    for (int j = 0; j < 4; ++j) {
        int i = base + j * 256 + t;
        if (i < N_NODES) s += degi[i];
    }
    lds[t] = s;
    __syncthreads();
    for (int off = 128; off > 0; off >>= 1) {
        if (t < off) lds[t] += lds[t + off];
        __syncthreads();
    }
    if (t == 0) chunkSums[b] = lds[0];
}

// ---- scan level 2 ----
__global__ __launch_bounds__(128) void k_scan_sums(int* chunkSums) {
    __shared__ int lds[NCHUNK];
    int t = threadIdx.x;
    if (t < NCHUNK) lds[t] = chunkSums[t];
    __syncthreads();
    if (t == 0) {
        int run = 0;
        for (int i = 0; i < NCHUNK; ++i) { int c = lds[i]; lds[i] = run; run += c; }
    }
    __syncthreads();
    if (t < NCHUNK) chunkSums[t] = lds[t];
}

// ---- scan level 3 (+ dinv fused) ----
__global__ __launch_bounds__(256) void k_scan_final(const int* __restrict__ degi,
                                                    const int* __restrict__ chunkOff,
                                                    int* __restrict__ rowptr,
                                                    int* __restrict__ cursor,
                                                    float* __restrict__ dinv) {
    __shared__ int tsum[256];
    int b = blockIdx.x, t = threadIdx.x;
    int base = b * SCAN_CHUNK;
    int v[4];
    int s = 0;
#pragma unroll
    for (int j = 0; j < 4; ++j) {
        int i = base + t * 4 + j;
        v[j] = (i < N_NODES) ? degi[i] : 0;
        s += v[j];
    }
    tsum[t] = s;
    __syncthreads();
    for (int off = 1; off < 256; off <<= 1) {
        int val = 0;
        if (t >= off) val = tsum[t - off];
        __syncthreads();
        if (t >= off) tsum[t] += val;
        __syncthreads();
    }
    int run = chunkOff[b] + ((t == 0) ? 0 : tsum[t - 1]);
#pragma unroll
    for (int j = 0; j < 4; ++j) {
        int i = base + t * 4 + j;
        if (i < N_NODES) {
            rowptr[i] = run;
            cursor[i] = run;
            dinv[i] = rsqrtf((float)v[j] + 1.0f);
        }
        run += v[j];
    }
    if (b == 0 && t == 0) rowptr[N_NODES] = N_EDGES;
}

// ---- CSR fill, XCD-bucketed (blockIdx&7 -> dst bucket) ----
__global__ __launch_bounds__(256) void k_fill_bucket(const int* __restrict__ eidx,
                                                     int* cursor, int* __restrict__ csr_src) {
    const int bucket = blockIdx.x & 7;
    const int chunk = blockIdx.x >> 3;
    const int nchunks = gridDim.x >> 3;
    const int lo = bucket * (N_NODES / 8);
    const int hi = lo + (N_NODES / 8);
    for (int e = chunk * 256 + threadIdx.x; e < N_EDGES; e += nchunks * 256) {
        int d = eidx[N_EDGES + e];
        if (d >= lo && d < hi) {
            int s = eidx[e];
            int pos = atomicAdd(&cursor[d], 1);
            csr_src[pos] = s;
        }
    }
}

// ---- weight converts (merged): W1t [128][256] bf16, W2t [48][128] bf16 ----
__global__ void k_cvt_w(const float* __restrict__ W1, const float* __restrict__ W2,
                        short* __restrict__ W1t, short* __restrict__ W2t) {
    int b = blockIdx.x, t = threadIdx.x;
    if (b < 128) {
        int idx = b * 256 + t;                 // 32768
        int n = idx >> 8, k = idx & 255;
        W1t[n * 256 + k] = (short)f2bf(W1[k * 128 + n]);
    } else {
        int idx = (b - 128) * 256 + t;         // 6144
        if (idx < 48 * 128) {
            int n = idx >> 7, k = idx & 127;
            float v = (n < F_OUT) ? W2[k * F_OUT + n] : 0.f;
            W2t[n * 128 + k] = (short)f2bf(v);
        }
    }
}

// ---- GEMM1 (MFMA bf16): h1f8[N,128](fp8) = dinv[row] * (x[N,256] @ W1) ----
__global__ __launch_bounds__(256) void k_gemm1_mfma(const float* __restrict__ x,
                                                    const short* __restrict__ W1t,
                                                    const float* __restrict__ dinv,
                                                    unsigned char* __restrict__ h1f8) {
    __shared__ short As[64 * 40];    // row stride 40 bf16 (80 B): 2-way banks, free
    __shared__ short Bs[128 * 40];
    __shared__ float Ds[64];
    const int tid = threadIdx.x;
    const int row0 = blockIdx.x * 64;
    const int w = tid >> 6, l = tid & 63;
    const int l15 = l & 15, q = l >> 4;
    const int ar = tid >> 2;             // 0..63
    const int ak = (tid & 3) * 8;        // 0,8,16,24
    const int bn = tid >> 1;             // 0..127
    const int bk = (tid & 1) * 16;

    if (tid < 64) {
        int r = row0 + tid;
        Ds[tid] = (r < N_NODES) ? dinv[r] : 0.f;
    }

    floatx4 acc[4][2];
#pragma unroll
    for (int mt = 0; mt < 4; ++mt)
#pragma unroll
        for (int nt = 0; nt < 2; ++nt) acc[mt][nt] = (floatx4)0.f;

    const bool arow_ok = (row0 + ar) < N_NODES;
    const float* xp = x + (size_t)(row0 + ar) * F_IN;

    for (int k0 = 0; k0 < F_IN; k0 += 32) {
        bf16x8 av;
        if (arow_ok) {
            float4 f0 = *(const float4*)(xp + k0 + ak);
            float4 f1 = *(const float4*)(xp + k0 + ak + 4);
            av[0] = (short)f2bf(f0.x); av[1] = (short)f2bf(f0.y);
            av[2] = (short)f2bf(f0.z); av[3] = (short)f2bf(f0.w);
            av[4] = (short)f2bf(f1.x); av[5] = (short)f2bf(f1.y);
            av[6] = (short)f2bf(f1.z); av[7] = (short)f2bf(f1.w);
        } else {
            av = (bf16x8)0;
        }
        *(bf16x8*)&As[ar * 40 + ak] = av;
        *(bf16x8*)&Bs[bn * 40 + bk]     = *(const bf16x8*)&W1t[bn * 256 + k0 + bk];
        *(bf16x8*)&Bs[bn * 40 + bk + 8] = *(const bf16x8*)&W1t[bn * 256 + k0 + bk + 8];
        __syncthreads();

        bf16x8 af[4], bfr[2];
#pragma unroll
        for (int mt = 0; mt < 4; ++mt)
            af[mt] = *(const bf16x8*)&As[(mt * 16 + l15) * 40 + q * 8];
#pragma unroll
        for (int nt = 0; nt < 2; ++nt)
            bfr[nt] = *(const bf16x8*)&Bs[(w * 32 + nt * 16 + l15) * 40 + q * 8];
#pragma unroll
        for (int mt = 0; mt < 4; ++mt)
#pragma unroll
            for (int nt = 0; nt < 2; ++nt)
                acc[mt][nt] = __builtin_amdgcn_mfma_f32_16x16x32_bf16(af[mt], bfr[nt], acc[mt][nt], 0, 0, 0);
        __syncthreads();
    }
#pragma unroll
    for (int mt = 0; mt < 4; ++mt) {
#pragma unroll
        for (int nt = 0; nt < 2; ++nt) {
            int col = w * 32 + nt * 16 + l15;
#pragma unroll
            for (int r = 0; r < 4; ++r) {
                int rl = mt * 16 + q * 4 + r;
                int row = row0 + rl;
                if (row < N_NODES)
                    h1f8[(size_t)row * F_H + col] = f2f8(acc[mt][nt][r] * Ds[rl]);
            }
        }
    }
}

// ---- SpMM1: wave per node, lane l = feature pair [2l,2l+1]; fp8 gather ----
// agg1 = relu( dinv[d] * sum(h1s) + b1 ), h1s pre-scaled by dinv[src]
__global__ __launch_bounds__(256) void k_spmm1(const int* __restrict__ rowptr,
                                               const int* __restrict__ csr_src,
                                               const unsigned short* __restrict__ h1p,  // h1f8 as ushorts
                                               const float* __restrict__ dinv,
                                               const float* __restrict__ b1,
                                               unsigned int* __restrict__ agg1p) {
    int wave = threadIdx.x >> 6;
    int node = blockIdx.x * 4 + wave;
    int l = threadIdx.x & 63;
    if (node >= N_NODES) return;
    int beg = rowptr[node], end = rowptr[node + 1];
    float d = dinv[node];
    floatx2 sv = f8x2tof(h1p[(size_t)node * 64 + l]);   // self loop (pre-scaled)
    float aL0 = sv.x, aH0 = sv.y;
    float aL1 = 0.f, aH1 = 0.f, aL2 = 0.f, aH2 = 0.f, aL3 = 0.f, aH3 = 0.f;
    int i = beg;
    for (; i + 3 < end; i += 4) {
        int s0 = csr_src[i], s1 = csr_src[i + 1], s2 = csr_src[i + 2], s3 = csr_src[i + 3];
        floatx2 v0 = f8x2tof(h1p[(size_t)s0 * 64 + l]);
        floatx2 v1 = f8x2tof(h1p[(size_t)s1 * 64 + l]);
        floatx2 v2 = f8x2tof(h1p[(size_t)s2 * 64 + l]);
        floatx2 v3 = f8x2tof(h1p[(size_t)s3 * 64 + l]);
        aL0 += v0.x; aH0 += v0.y;
        aL1 += v1.x; aH1 += v1.y;
        aL2 += v2.x; aH2 += v2.y;
        aL3 += v3.x; aH3 += v3.y;
    }
    for (; i < end; ++i) {
        floatx2 v0 = f8x2tof(h1p[(size_t)csr_src[i] * 64 + l]);
        aL0 += v0.x; aH0 += v0.y;
    }
    float vL = fmaf((aL0 + aL1) + (aL2 + aL3), d, b1[2 * l]);
    float vH = fmaf((aH0 + aH1) + (aH2 + aH3), d, b1[2 * l + 1]);
    vL = vL > 0.f ? vL : 0.f;
    vH = vH > 0.f ? vH : 0.f;
    agg1p[(size_t)node * 64 + l] = ((unsigned int)f2bf(vH) << 16) | f2bf(vL);
}

// ---- GEMM2 (MFMA bf16): h2f8[N,40](fp8) = dinv[row] * (agg1b[N,128] @ W2) ----
__global__ __launch_bounds__(256) void k_gemm2_mfma(const unsigned short* __restrict__ agg1b,
                                                    const short* __restrict__ W2t,
                                                    const float* __restrict__ dinv,
                                                    unsigned char* __restrict__ h2f8) {
    __shared__ short As[128 * 40];     // 10 KB
    __shared__ short Bs[48 * 136];     // 12.75 KB
    __shared__ float Ds[128];
    const int tid = threadIdx.x;
    const int row0 = blockIdx.x * 128;
    const int w = tid >> 6, l = tid & 63;
    const int l15 = l & 15, q = l >> 4;
    const int ar = tid >> 1;             // 0..127
    const int ak = (tid & 1) * 16;

#pragma unroll
    for (int i = 0; i < 3; ++i) {
        int c = tid * 3 + i;             // 0..767 chunks of 8 bf16
        int n = c >> 4, koff = (c & 15) * 8;
        *(bf16x8*)&Bs[n * 136 + koff] = *(const bf16x8*)&W2t[n * 128 + koff];
    }
    if (tid < 128) {
        int r = row0 + tid;
        Ds[tid] = (r < N_NODES) ? dinv[r] : 0.f;
    }

    floatx4 acc[2][3];
#pragma unroll
    for (int a = 0; a < 2; ++a)
#pragma unroll
        for (int nt = 0; nt < 3; ++nt) acc[a][nt] = (floatx4)0.f;

    const bool arow_ok = (row0 + ar) < N_NODES;
    const unsigned short* ap = agg1b + (size_t)(row0 + ar) * F_H;

    for (int k0 = 0; k0 < F_H; k0 += 32) {
        bf16x8 a0, a1;
        if (arow_ok) {
            a0 = *(const bf16x8*)(ap + k0 + ak);
            a1 = *(const bf16x8*)(ap + k0 + ak + 8);
        } else {
            a0 = (bf16x8)0; a1 = (bf16x8)0;
        }
        *(bf16x8*)&As[ar * 40 + ak]     = a0;
        *(bf16x8*)&As[ar * 40 + ak + 8] = a1;
        __syncthreads();

        bf16x8 af[2], bfr[3];
#pragma unroll
        for (int a = 0; a < 2; ++a)
            af[a] = *(const bf16x8*)&As[((w * 2 + a) * 16 + l15) * 40 + q * 8];
#pragma unroll
        for (int nt = 0; nt < 3; ++nt)
            bfr[nt] = *(const bf16x8*)&Bs[(nt * 16 + l15) * 136 + k0 + q * 8];
#pragma unroll
        for (int a = 0; a < 2; ++a)
#pragma unroll
            for (int nt = 0; nt < 3; ++nt)
                acc[a][nt] = __builtin_amdgcn_mfma_f32_16x16x32_bf16(af[a], bfr[nt], acc[a][nt], 0, 0, 0);
        __syncthreads();
    }
#pragma unroll
    for (int a = 0; a < 2; ++a) {
#pragma unroll
        for (int nt = 0; nt < 3; ++nt) {
            int col = nt * 16 + l15;
#pragma unroll
            for (int r = 0; r < 4; ++r) {
                int rl = (w * 2 + a) * 16 + q * 4 + r;
                int row = row0 + rl;
                if (row < N_NODES && col < F_OUT)
                    h2f8[(size_t)row * F_OUT + col] = f2f8(acc[a][nt][r] * Ds[rl]);
            }
        }
    }
}

// ---- SpMM2 (fp8 gather) + b2 + log_softmax, wave per node ----
__global__ __launch_bounds__(256) void k_spmm2_lsm(const int* __restrict__ rowptr,
                                                   const int* __restrict__ csr_src,
                                                   const unsigned char* __restrict__ h2f8,
                                                   const float* __restrict__ dinv,
                                                   const float* __restrict__ b2,
                                                   float* __restrict__ out) {
    int wave = threadIdx.x >> 6;
    int node = blockIdx.x * 4 + wave;
    int lane = threadIdx.x & 63;
    if (node >= N_NODES) return;
    int beg = rowptr[node], end = rowptr[node + 1];
    float d = dinv[node];
    const bool act = lane < F_OUT;
    float a0 = 0.f, a1 = 0.f, a2 = 0.f, a3 = 0.f;
    if (act) a0 = f82f(h2f8[(size_t)node * F_OUT + lane]);   // self loop (pre-scaled)
    int i = beg;
    for (; i + 3 < end; i += 4) {
        int s0 = csr_src[i], s1 = csr_src[i + 1], s2 = csr_src[i + 2], s3 = csr_src[i + 3];
        if (act) {
            a0 += f82f(h2f8[(size_t)s0 * F_OUT + lane]);
            a1 += f82f(h2f8[(size_t)s1 * F_OUT + lane]);
            a2 += f82f(h2f8[(size_t)s2 * F_OUT + lane]);
            a3 += f82f(h2f8[(size_t)s3 * F_OUT + lane]);
        }
    }
    for (; i < end; ++i) {
        if (act) a0 += f82f(h2f8[(size_t)csr_src[i] * F_OUT + lane]);
    }
    float v = act ? fmaf((a0 + a1) + (a2 + a3), d, b2[lane]) : -INFINITY;
    float m = v;
#pragma unroll
    for (int o = 32; o > 0; o >>= 1) m = fmaxf(m, __shfl_xor(m, o, 64));
    float ev = act ? expf(v - m) : 0.f;
    float ssum = ev;
#pragma unroll
    for (int o = 32; o > 0; o >>= 1) ssum += __shfl_xor(ssum, o, 64);
    if (act) out[(size_t)node * F_OUT + lane] = v - m - logf(ssum);
}

extern "C" void kernel_launch(void* const* d_in, const int* in_sizes, int n_in,
                              void* d_out, int out_size, void* d_ws, size_t ws_size,
                              hipStream_t stream) {
    const float* x = (const float*)d_in[0];
    const int* eidx = (const int*)d_in[1];   // int32 from harness
    const float* W1 = (const float*)d_in[2];
    const float* b1 = (const float*)d_in[3];
    const float* W2 = (const float*)d_in[4];
    const float* b2 = (const float*)d_in[5];
    float* out = (float*)d_out;

    char* ws = (char*)d_ws;
    int*   degi      = (int*)  (ws);                 // 100000 ints
    int*   chunkSums = (int*)  (ws + 400000);        // 128
    int*   rowptr    = (int*)  (ws + 400512);        // 100001
    int*   cursor    = (int*)  (ws + 800528);        // 100000
    int*   csr_src   = (int*)  (ws + 1200528);       // 1.6M ints
    float* dinv      = (float*)(ws + 7600528);       // 100000
    short* W1t       = (short*)(ws + 8000528);       // 32768 bf16
    short* W2t       = (short*)(ws + 8066064);       // 6144 bf16
    unsigned char*  h1f8  = (unsigned char*) (ws + 8078352);   // 12.8M fp8 (12.8 MB)
    unsigned short* agg1b = (unsigned short*)(ws + 20878352);  // 12.8M bf16 (25.6 MB)
    unsigned char*  h2f8  = (unsigned char*) (ws + 46478352);  // 4M fp8 (4 MB)

    k_zero<<<(N_NODES + 255) / 256, 256, 0, stream>>>(degi, N_NODES);
    k_deg<<<(N_EDGES + 255) / 256, 256, 0, stream>>>(eidx, degi);
    k_chunk_sums<<<NCHUNK, 256, 0, stream>>>(degi, chunkSums);
    k_scan_sums<<<1, 128, 0, stream>>>(chunkSums);
    k_scan_final<<<NCHUNK, 256, 0, stream>>>(degi, chunkSums, rowptr, cursor, dinv);
    k_fill_bucket<<<4096, 256, 0, stream>>>(eidx, cursor, csr_src);

    k_cvt_w<<<152, 256, 0, stream>>>(W1, W2, W1t, W2t);

    k_gemm1_mfma<<<(N_NODES + 63) / 64, 256, 0, stream>>>(x, W1t, dinv, h1f8);
    k_spmm1<<<(N_NODES + 3) / 4, 256, 0, stream>>>(rowptr, csr_src,
                                                   (const unsigned short*)h1f8, dinv, b1,
                                                   (unsigned int*)agg1b);
    k_gemm2_mfma<<<(N_NODES + 127) / 128, 256, 0, stream>>>(agg1b, W2t, dinv, h2f8);
    k_spmm2_lsm<<<(N_NODES + 3) / 4, 256, 0, stream>>>(rowptr, csr_src, h2f8, dinv, b2, out);
}

// Round 9
// 424.749 us; speedup vs baseline: 1.2995x; 1.1067x over previous
//
#include <hip/hip_runtime.h>
#include <hip/hip_fp8.h>
#include <math.h>

#define N_NODES 100000
#define N_EDGES 1600000
#define F_IN 256
#define F_H 128
#define F_OUT 40
#define SCAN_CHUNK 1024
#define NCHUNK ((N_NODES + SCAN_CHUNK - 1) / SCAN_CHUNK)   // 98

typedef __attribute__((ext_vector_type(8))) short bf16x8;
typedef __attribute__((ext_vector_type(4))) float floatx4;
typedef __attribute__((ext_vector_type(2))) float floatx2;
typedef __attribute__((ext_vector_type(2))) unsigned int uintx2;

__device__ __forceinline__ unsigned short f2bf(float f) {
    unsigned int u = __float_as_uint(f);
    u += 0x7fffu + ((u >> 16) & 1u);          // RNE (finite inputs)
    return (unsigned short)(u >> 16);
}
__device__ __forceinline__ float bf2f(unsigned short s) { return __uint_as_float(((unsigned int)s) << 16); }

// ---- fp8 e4m3 (OCP) encode/decode, native cvt when available ----
#if defined(__has_builtin)
#if __has_builtin(__builtin_amdgcn_cvt_pk_fp8_f32)
#define HAVE_PK_ENC 1
#endif
#if __has_builtin(__builtin_amdgcn_cvt_pk_f32_fp8)
#define HAVE_PK_DEC 1
#endif
#if __has_builtin(__builtin_amdgcn_cvt_f32_fp8)
#define HAVE_SC_DEC 1
#endif
#endif

__device__ __forceinline__ unsigned char f2f8(float f) {
#ifdef HAVE_PK_ENC
    int r = __builtin_amdgcn_cvt_pk_fp8_f32(f, f, 0, false);
    return (unsigned char)(r & 0xff);
#else
    __hip_fp8_e4m3 t(f);
    return (unsigned char)t.__x;
#endif
}
__device__ __forceinline__ float f82f(unsigned char b) {
#ifdef HAVE_SC_DEC
    return __builtin_amdgcn_cvt_f32_fp8((int)b, 0);
#else
    __hip_fp8_e4m3 t; t.__x = (__hip_fp8_storage_t)b;
    return (float)t;
#endif
}
__device__ __forceinline__ floatx2 f8x2tof(unsigned short u) {
#ifdef HAVE_PK_DEC
    return __builtin_amdgcn_cvt_pk_f32_fp8((int)u, false);
#else
    floatx2 r;
    r.x = f82f((unsigned char)(u & 0xff));
    r.y = f82f((unsigned char)(u >> 8));
    return r;
#endif
}

// ---- zero int array ----
__global__ void k_zero(int* p, int n) {
    int i = blockIdx.x * blockDim.x + threadIdx.x;
    if (i < n) p[i] = 0;
}

// ---- int degree count over dst ----
__global__ void k_deg(const int* __restrict__ eidx, int* degi) {
    int e = blockIdx.x * blockDim.x + threadIdx.x;
    if (e < N_EDGES) atomicAdd(&degi[eidx[N_EDGES + e]], 1);
}

// ---- scan level 1 ----
__global__ __launch_bounds__(256) void k_chunk_sums(const int* __restrict__ degi,
                                                    int* __restrict__ chunkSums) {
    __shared__ int lds[256];
    int b = blockIdx.x, t = threadIdx.x;
    int base = b * SCAN_CHUNK;
    int s = 0;
#pragma unroll
    for (int j = 0; j < 4; ++j) {
        int i = base + j * 256 + t;
        if (i < N_NODES) s += degi[i];
    }
    lds[t] = s;
    __syncthreads();
    for (int off = 128; off > 0; off >>= 1) {
        if (t < off) lds[t] += lds[t + off];
        __syncthreads();
    }
    if (t == 0) chunkSums[b] = lds[0];
}

// ---- scan level 2 ----
__global__ __launch_bounds__(128) void k_scan_sums(int* chunkSums) {
    __shared__ int lds[NCHUNK];
    int t = threadIdx.x;
    if (t < NCHUNK) lds[t] = chunkSums[t];
    __syncthreads();
    if (t == 0) {
        int run = 0;
        for (int i = 0; i < NCHUNK; ++i) { int c = lds[i]; lds[i] = run; run += c; }
    }
    __syncthreads();
    if (t < NCHUNK) chunkSums[t] = lds[t];
}

// ---- scan level 3 (+ dinv fused) ----
__global__ __launch_bounds__(256) void k_scan_final(const int* __restrict__ degi,
                                                    const int* __restrict__ chunkOff,
                                                    int* __restrict__ rowptr,
                                                    int* __restrict__ cursor,
                                                    float* __restrict__ dinv) {
    __shared__ int tsum[256];
    int b = blockIdx.x, t = threadIdx.x;
    int base = b * SCAN_CHUNK;
    int v[4];
    int s = 0;
#pragma unroll
    for (int j = 0; j < 4; ++j) {
        int i = base + t * 4 + j;
        v[j] = (i < N_NODES) ? degi[i] : 0;
        s += v[j];
    }
    tsum[t] = s;
    __syncthreads();
    for (int off = 1; off < 256; off <<= 1) {
        int val = 0;
        if (t >= off) val = tsum[t - off];
        __syncthreads();
        if (t >= off) tsum[t] += val;
        __syncthreads();
    }
    int run = chunkOff[b] + ((t == 0) ? 0 : tsum[t - 1]);
#pragma unroll
    for (int j = 0; j < 4; ++j) {
        int i = base + t * 4 + j;
        if (i < N_NODES) {
            rowptr[i] = run;
            cursor[i] = run;
            dinv[i] = rsqrtf((float)v[j] + 1.0f);
        }
        run += v[j];
    }
    if (b == 0 && t == 0) rowptr[N_NODES] = N_EDGES;
}

// ---- CSR fill, XCD-bucketed (blockIdx&7 -> dst bucket) ----
__global__ __launch_bounds__(256) void k_fill_bucket(const int* __restrict__ eidx,
                                                     int* cursor, int* __restrict__ csr_src) {
    const int bucket = blockIdx.x & 7;
    const int chunk = blockIdx.x >> 3;
    const int nchunks = gridDim.x >> 3;
    const int lo = bucket * (N_NODES / 8);
    const int hi = lo + (N_NODES / 8);
    for (int e = chunk * 256 + threadIdx.x; e < N_EDGES; e += nchunks * 256) {
        int d = eidx[N_EDGES + e];
        if (d >= lo && d < hi) {
            int s = eidx[e];
            int pos = atomicAdd(&cursor[d], 1);
            csr_src[pos] = s;
        }
    }
}

// ---- weight converts (merged): W1t [128][256] bf16, W2t [48][128] bf16 ----
__global__ void k_cvt_w(const float* __restrict__ W1, const float* __restrict__ W2,
                        short* __restrict__ W1t, short* __restrict__ W2t) {
    int b = blockIdx.x, t = threadIdx.x;
    if (b < 128) {
        int idx = b * 256 + t;                 // 32768
        int n = idx >> 8, k = idx & 255;
        W1t[n * 256 + k] = (short)f2bf(W1[k * 128 + n]);
    } else {
        int idx = (b - 128) * 256 + t;         // 6144
        if (idx < 48 * 128) {
            int n = idx >> 7, k = idx & 127;
            float v = (n < F_OUT) ? W2[k * F_OUT + n] : 0.f;
            W2t[n * 128 + k] = (short)f2bf(v);
        }
    }
}

// ---- GEMM1 (MFMA bf16): h1f8[N,128](fp8) = dinv[row] * (x[N,256] @ W1) ----
__global__ __launch_bounds__(256) void k_gemm1_mfma(const float* __restrict__ x,
                                                    const short* __restrict__ W1t,
                                                    const float* __restrict__ dinv,
                                                    unsigned char* __restrict__ h1f8) {
    __shared__ short As[64 * 40];    // row stride 40 bf16 (80 B): 2-way banks, free
    __shared__ short Bs[128 * 40];
    __shared__ float Ds[64];
    const int tid = threadIdx.x;
    const int row0 = blockIdx.x * 64;
    const int w = tid >> 6, l = tid & 63;
    const int l15 = l & 15, q = l >> 4;
    const int ar = tid >> 2;             // 0..63
    const int ak = (tid & 3) * 8;        // 0,8,16,24
    const int bn = tid >> 1;             // 0..127
    const int bk = (tid & 1) * 16;

    if (tid < 64) {
        int r = row0 + tid;
        Ds[tid] = (r < N_NODES) ? dinv[r] : 0.f;
    }

    floatx4 acc[4][2];
#pragma unroll
    for (int mt = 0; mt < 4; ++mt)
#pragma unroll
        for (int nt = 0; nt < 2; ++nt) acc[mt][nt] = (floatx4)0.f;

    const bool arow_ok = (row0 + ar) < N_NODES;
    const float* xp = x + (size_t)(row0 + ar) * F_IN;

    for (int k0 = 0; k0 < F_IN; k0 += 32) {
        bf16x8 av;
        if (arow_ok) {
            float4 f0 = *(const float4*)(xp + k0 + ak);
            float4 f1 = *(const float4*)(xp + k0 + ak + 4);
            av[0] = (short)f2bf(f0.x); av[1] = (short)f2bf(f0.y);
            av[2] = (short)f2bf(f0.z); av[3] = (short)f2bf(f0.w);
            av[4] = (short)f2bf(f1.x); av[5] = (short)f2bf(f1.y);
            av[6] = (short)f2bf(f1.z); av[7] = (short)f2bf(f1.w);
        } else {
            av = (bf16x8)0;
        }
        *(bf16x8*)&As[ar * 40 + ak] = av;
        *(bf16x8*)&Bs[bn * 40 + bk]     = *(const bf16x8*)&W1t[bn * 256 + k0 + bk];
        *(bf16x8*)&Bs[bn * 40 + bk + 8] = *(const bf16x8*)&W1t[bn * 256 + k0 + bk + 8];
        __syncthreads();

        bf16x8 af[4], bfr[2];
#pragma unroll
        for (int mt = 0; mt < 4; ++mt)
            af[mt] = *(const bf16x8*)&As[(mt * 16 + l15) * 40 + q * 8];
#pragma unroll
        for (int nt = 0; nt < 2; ++nt)
            bfr[nt] = *(const bf16x8*)&Bs[(w * 32 + nt * 16 + l15) * 40 + q * 8];
#pragma unroll
        for (int mt = 0; mt < 4; ++mt)
#pragma unroll
            for (int nt = 0; nt < 2; ++nt)
                acc[mt][nt] = __builtin_amdgcn_mfma_f32_16x16x32_bf16(af[mt], bfr[nt], acc[mt][nt], 0, 0, 0);
        __syncthreads();
    }
#pragma unroll
    for (int mt = 0; mt < 4; ++mt) {
#pragma unroll
        for (int nt = 0; nt < 2; ++nt) {
            int col = w * 32 + nt * 16 + l15;
#pragma unroll
            for (int r = 0; r < 4; ++r) {
                int rl = mt * 16 + q * 4 + r;
                int row = row0 + rl;
                if (row < N_NODES)
                    h1f8[(size_t)row * F_H + col] = f2f8(acc[mt][nt][r] * Ds[rl]);
            }
        }
    }
}

// ---- SpMM1: HALF-WAVE (32 lanes) per node; lane p loads dword = 4 fp8 feats ----
// agg1 = relu( dinv[d] * sum(h1s) + b1 ), h1s pre-scaled by dinv[src]
__global__ __launch_bounds__(256) void k_spmm1(const int* __restrict__ rowptr,
                                               const int* __restrict__ csr_src,
                                               const unsigned int* __restrict__ h1d,  // fp8 rows as 32 dwords
                                               const float* __restrict__ dinv,
                                               const float* __restrict__ b1,
                                               uintx2* __restrict__ agg1p2) {        // bf16 rows as 32 uint2
    const int half = threadIdx.x >> 5;        // 0..7 node slot in block
    const int p = threadIdx.x & 31;           // dword index in row
    int node = blockIdx.x * 8 + half;
    bool valid = node < N_NODES;
    int nd = valid ? node : 0;
    int beg = rowptr[nd];
    int end = valid ? rowptr[nd + 1] : beg;
    float dv = dinv[nd];

    unsigned int su = h1d[(size_t)nd * 32 + p];
    floatx2 s01 = f8x2tof((unsigned short)(su & 0xffffu));
    floatx2 s23 = f8x2tof((unsigned short)(su >> 16));
    float A0 = s01.x, A1 = s01.y, A2 = s23.x, A3 = s23.y;   // self loop
    float B0 = 0.f, B1 = 0.f, B2 = 0.f, B3 = 0.f;
    float C0 = 0.f, C1 = 0.f, C2 = 0.f, C3 = 0.f;
    float D0 = 0.f, D1 = 0.f, D2 = 0.f, D3 = 0.f;

    int i = beg;
    for (; i + 3 < end; i += 4) {
        int s0 = csr_src[i], s1 = csr_src[i + 1], s2 = csr_src[i + 2], s3 = csr_src[i + 3];
        unsigned int u0 = h1d[(size_t)s0 * 32 + p];
        unsigned int u1 = h1d[(size_t)s1 * 32 + p];
        unsigned int u2 = h1d[(size_t)s2 * 32 + p];
        unsigned int u3 = h1d[(size_t)s3 * 32 + p];
        floatx2 a01 = f8x2tof((unsigned short)(u0 & 0xffffu));
        floatx2 a23 = f8x2tof((unsigned short)(u0 >> 16));
        floatx2 b01 = f8x2tof((unsigned short)(u1 & 0xffffu));
        floatx2 b23 = f8x2tof((unsigned short)(u1 >> 16));
        floatx2 c01 = f8x2tof((unsigned short)(u2 & 0xffffu));
        floatx2 c23 = f8x2tof((unsigned short)(u2 >> 16));
        floatx2 d01 = f8x2tof((unsigned short)(u3 & 0xffffu));
        floatx2 d23 = f8x2tof((unsigned short)(u3 >> 16));
        A0 += a01.x; A1 += a01.y; A2 += a23.x; A3 += a23.y;
        B0 += b01.x; B1 += b01.y; B2 += b23.x; B3 += b23.y;
        C0 += c01.x; C1 += c01.y; C2 += c23.x; C3 += c23.y;
        D0 += d01.x; D1 += d01.y; D2 += d23.x; D3 += d23.y;
    }
    for (; i < end; ++i) {
        unsigned int u0 = h1d[(size_t)csr_src[i] * 32 + p];
        floatx2 a01 = f8x2tof((unsigned short)(u0 & 0xffffu));
        floatx2 a23 = f8x2tof((unsigned short)(u0 >> 16));
        A0 += a01.x; A1 += a01.y; A2 += a23.x; A3 += a23.y;
    }

    float4 bb = *(const float4*)&b1[4 * p];
    float v0 = fmaf((A0 + B0) + (C0 + D0), dv, bb.x);
    float v1 = fmaf((A1 + B1) + (C1 + D1), dv, bb.y);
    float v2 = fmaf((A2 + B2) + (C2 + D2), dv, bb.z);
    float v3 = fmaf((A3 + B3) + (C3 + D3), dv, bb.w);
    v0 = v0 > 0.f ? v0 : 0.f;
    v1 = v1 > 0.f ? v1 : 0.f;
    v2 = v2 > 0.f ? v2 : 0.f;
    v3 = v3 > 0.f ? v3 : 0.f;
    if (valid) {
        uintx2 o;
        o.x = ((unsigned int)f2bf(v1) << 16) | f2bf(v0);
        o.y = ((unsigned int)f2bf(v3) << 16) | f2bf(v2);
        agg1p2[(size_t)node * 32 + p] = o;
    }
}

// ---- GEMM2 (MFMA bf16): h2f8[N,40](fp8) = dinv[row] * (agg1b[N,128] @ W2) ----
__global__ __launch_bounds__(256) void k_gemm2_mfma(const unsigned short* __restrict__ agg1b,
                                                    const short* __restrict__ W2t,
                                                    const float* __restrict__ dinv,
                                                    unsigned char* __restrict__ h2f8) {
    __shared__ short As[128 * 40];     // 10 KB
    __shared__ short Bs[48 * 136];     // 12.75 KB
    __shared__ float Ds[128];
    const int tid = threadIdx.x;
    const int row0 = blockIdx.x * 128;
    const int w = tid >> 6, l = tid & 63;
    const int l15 = l & 15, q = l >> 4;
    const int ar = tid >> 1;             // 0..127
    const int ak = (tid & 1) * 16;

#pragma unroll
    for (int i = 0; i < 3; ++i) {
        int c = tid * 3 + i;             // 0..767 chunks of 8 bf16
        int n = c >> 4, koff = (c & 15) * 8;
        *(bf16x8*)&Bs[n * 136 + koff] = *(const bf16x8*)&W2t[n * 128 + koff];
    }
    if (tid < 128) {
        int r = row0 + tid;
        Ds[tid] = (r < N_NODES) ? dinv[r] : 0.f;
    }

    floatx4 acc[2][3];
#pragma unroll
    for (int a = 0; a < 2; ++a)
#pragma unroll
        for (int nt = 0; nt < 3; ++nt) acc[a][nt] = (floatx4)0.f;

    const bool arow_ok = (row0 + ar) < N_NODES;
    const unsigned short* ap = agg1b + (size_t)(row0 + ar) * F_H;

    for (int k0 = 0; k0 < F_H; k0 += 32) {
        bf16x8 a0, a1;
        if (arow_ok) {
            a0 = *(const bf16x8*)(ap + k0 + ak);
            a1 = *(const bf16x8*)(ap + k0 + ak + 8);
        } else {
            a0 = (bf16x8)0; a1 = (bf16x8)0;
        }
        *(bf16x8*)&As[ar * 40 + ak]     = a0;
        *(bf16x8*)&As[ar * 40 + ak + 8] = a1;
        __syncthreads();

        bf16x8 af[2], bfr[3];
#pragma unroll
        for (int a = 0; a < 2; ++a)
            af[a] = *(const bf16x8*)&As[((w * 2 + a) * 16 + l15) * 40 + q * 8];
#pragma unroll
        for (int nt = 0; nt < 3; ++nt)
            bfr[nt] = *(const bf16x8*)&Bs[(nt * 16 + l15) * 136 + k0 + q * 8];
#pragma unroll
        for (int a = 0; a < 2; ++a)
#pragma unroll
            for (int nt = 0; nt < 3; ++nt)
                acc[a][nt] = __builtin_amdgcn_mfma_f32_16x16x32_bf16(af[a], bfr[nt], acc[a][nt], 0, 0, 0);
        __syncthreads();
    }
#pragma unroll
    for (int a = 0; a < 2; ++a) {
#pragma unroll
        for (int nt = 0; nt < 3; ++nt) {
            int col = nt * 16 + l15;
#pragma unroll
            for (int r = 0; r < 4; ++r) {
                int rl = (w * 2 + a) * 16 + q * 4 + r;
                int row = row0 + rl;
                if (row < N_NODES && col < F_OUT)
                    h2f8[(size_t)row * F_OUT + col] = f2f8(acc[a][nt][r] * Ds[rl]);
            }
        }
    }
}

// ---- SpMM2 + log_softmax: QUARTER-WAVE (16 lanes) per node; lanes 0..9 load dwords ----
__global__ __launch_bounds__(256) void k_spmm2_lsm(const int* __restrict__ rowptr,
                                                   const int* __restrict__ csr_src,
                                                   const unsigned int* __restrict__ h2d,  // fp8 rows as 10 dwords
                                                   const float* __restrict__ dinv,
                                                   const float* __restrict__ b2,
                                                   float* __restrict__ out) {
    const int qid = threadIdx.x >> 4;         // 0..15 node slot in block
    const int p = threadIdx.x & 15;           // dword index (active p<10)
    int node = blockIdx.x * 16 + qid;
    bool nvalid = node < N_NODES;
    bool valid = nvalid && (p < 10);
    int nd = nvalid ? node : 0;
    int beg = 0, end = 0;
    if (valid) { beg = rowptr[nd]; end = rowptr[nd + 1]; }
    float dv = dinv[nd];

    float A0 = 0.f, A1 = 0.f, A2 = 0.f, A3 = 0.f;
    float B0 = 0.f, B1 = 0.f, B2 = 0.f, B3 = 0.f;
    if (valid) {
        unsigned int su = h2d[(size_t)nd * 10 + p];
        floatx2 t0 = f8x2tof((unsigned short)(su & 0xffffu));
        floatx2 t1 = f8x2tof((unsigned short)(su >> 16));
        A0 = t0.x; A1 = t0.y; A2 = t1.x; A3 = t1.y;   // self loop
    }
    int i = beg;
    for (; i + 1 < end; i += 2) {
        int s0 = csr_src[i], s1 = csr_src[i + 1];
        unsigned int u0 = h2d[(size_t)s0 * 10 + p];
        unsigned int u1 = h2d[(size_t)s1 * 10 + p];
        floatx2 a01 = f8x2tof((unsigned short)(u0 & 0xffffu));
        floatx2 a23 = f8x2tof((unsigned short)(u0 >> 16));
        floatx2 b01 = f8x2tof((unsigned short)(u1 & 0xffffu));
        floatx2 b23 = f8x2tof((unsigned short)(u1 >> 16));
        A0 += a01.x; A1 += a01.y; A2 += a23.x; A3 += a23.y;
        B0 += b01.x; B1 += b01.y; B2 += b23.x; B3 += b23.y;
    }
    if (i < end) {
        unsigned int u0 = h2d[(size_t)csr_src[i] * 10 + p];
        floatx2 a01 = f8x2tof((unsigned short)(u0 & 0xffffu));
        floatx2 a23 = f8x2tof((unsigned short)(u0 >> 16));
        A0 += a01.x; A1 += a01.y; A2 += a23.x; A3 += a23.y;
    }

    float v0 = -INFINITY, v1 = -INFINITY, v2 = -INFINITY, v3 = -INFINITY;
    if (valid) {
        float4 bb = *(const float4*)&b2[4 * p];
        v0 = fmaf(A0 + B0, dv, bb.x);
        v1 = fmaf(A1 + B1, dv, bb.y);
        v2 = fmaf(A2 + B2, dv, bb.z);
        v3 = fmaf(A3 + B3, dv, bb.w);
    }
    float m = fmaxf(fmaxf(v0, v1), fmaxf(v2, v3));
#pragma unroll
    for (int off = 1; off < 16; off <<= 1) m = fmaxf(m, __shfl_xor(m, off, 16));
    float e = 0.f;
    if (valid) e = expf(v0 - m) + expf(v1 - m) + expf(v2 - m) + expf(v3 - m);
#pragma unroll
    for (int off = 1; off < 16; off <<= 1) e += __shfl_xor(e, off, 16);
    if (valid) {
        float ls = logf(e);
        float4 o;
        o.x = v0 - m - ls; o.y = v1 - m - ls; o.z = v2 - m - ls; o.w = v3 - m - ls;
        *(float4*)&out[(size_t)node * F_OUT + 4 * p] = o;
    }
}

extern "C" void kernel_launch(void* const* d_in, const int* in_sizes, int n_in,
                              void* d_out, int out_size, void* d_ws, size_t ws_size,
                              hipStream_t stream) {
    const float* x = (const float*)d_in[0];
    const int* eidx = (const int*)d_in[1];   // int32 from harness
    const float* W1 = (const float*)d_in[2];
    const float* b1 = (const float*)d_in[3];
    const float* W2 = (const float*)d_in[4];
    const float* b2 = (const float*)d_in[5];
    float* out = (float*)d_out;

    char* ws = (char*)d_ws;
    int*   degi      = (int*)  (ws);                 // 100000 ints
    int*   chunkSums = (int*)  (ws + 400000);        // 128
    int*   rowptr    = (int*)  (ws + 400512);        // 100001
    int*   cursor    = (int*)  (ws + 800528);        // 100000
    int*   csr_src   = (int*)  (ws + 1200528);       // 1.6M ints
    float* dinv      = (float*)(ws + 7600528);       // 100000
    short* W1t       = (short*)(ws + 8000528);       // 32768 bf16
    short* W2t       = (short*)(ws + 8066064);       // 6144 bf16
    unsigned char*  h1f8  = (unsigned char*) (ws + 8078352);   // 12.8M fp8 (12.8 MB)
    unsigned short* agg1b = (unsigned short*)(ws + 20878352);  // 12.8M bf16 (25.6 MB)
    unsigned char*  h2f8  = (unsigned char*) (ws + 46478352);  // 4M fp8 (4 MB)

    k_zero<<<(N_NODES + 255) / 256, 256, 0, stream>>>(degi, N_NODES);
    k_deg<<<(N_EDGES + 255) / 256, 256, 0, stream>>>(eidx, degi);
    k_chunk_sums<<<NCHUNK, 256, 0, stream>>>(degi, chunkSums);
    k_scan_sums<<<1, 128, 0, stream>>>(chunkSums);
    k_scan_final<<<NCHUNK, 256, 0, stream>>>(degi, chunkSums, rowptr, cursor, dinv);
    k_fill_bucket<<<4096, 256, 0, stream>>>(eidx, cursor, csr_src);

    k_cvt_w<<<152, 256, 0, stream>>>(W1, W2, W1t, W2t);

    k_gemm1_mfma<<<(N_NODES + 63) / 64, 256, 0, stream>>>(x, W1t, dinv, h1f8);
    k_spmm1<<<(N_NODES + 7) / 8, 256, 0, stream>>>(rowptr, csr_src,
                                                   (const unsigned int*)h1f8, dinv, b1,
                                                   (uintx2*)agg1b);
    k_gemm2_mfma<<<(N_NODES + 127) / 128, 256, 0, stream>>>(agg1b, W2t, dinv, h2f8);
    k_spmm2_lsm<<<(N_NODES + 15) / 16, 256, 0, stream>>>(rowptr, csr_src,
                                                         (const unsigned int*)h2f8, dinv, b2, out);
}